// Round 2
// baseline (365.096 us; speedup 1.0000x reference)
//
#include <hip/hip_runtime.h>

// Problem constants: B=2, S=2048, D=1024, H=16, DK=64
#define S_LEN 2048
#define DMODEL 1024
#define DHEAD 64

typedef _Float16 half8 __attribute__((ext_vector_type(8)));
typedef float f32x4 __attribute__((ext_vector_type(4)));

#define LOG2E 1.4426950408889634f

// load 16 fp32 from global, convert to fp16, store 2x half8 to LDS
__device__ __forceinline__ void stage16_cvt(const float* __restrict__ gp, _Float16* lp) {
  float4 f0 = ((const float4*)gp)[0];
  float4 f1 = ((const float4*)gp)[1];
  float4 f2 = ((const float4*)gp)[2];
  float4 f3 = ((const float4*)gp)[3];
  half8 h0, h1;
  h0[0] = (_Float16)f0.x; h0[1] = (_Float16)f0.y; h0[2] = (_Float16)f0.z; h0[3] = (_Float16)f0.w;
  h0[4] = (_Float16)f1.x; h0[5] = (_Float16)f1.y; h0[6] = (_Float16)f1.z; h0[7] = (_Float16)f1.w;
  h1[0] = (_Float16)f2.x; h1[1] = (_Float16)f2.y; h1[2] = (_Float16)f2.z; h1[3] = (_Float16)f2.w;
  h1[4] = (_Float16)f3.x; h1[5] = (_Float16)f3.y; h1[6] = (_Float16)f3.z; h1[7] = (_Float16)f3.w;
  *(half8*)lp = h0;
  *(half8*)(lp + 8) = h1;
}

// ---------------- fused QKV projection GEMM ----------------
// C[m,n] = sum_k A[m,k] * W[n,k] + bias[n]; both operands fp32, converted in staging.
// blockIdx.y selects {Q,K,V}x{wq,wk,wv}. q output pre-scaled by 0.125 (exact pow2).
__global__ __launch_bounds__(256) void qkv_gemm(
    const float* __restrict__ Qf, const float* __restrict__ Kf, const float* __restrict__ Vf,
    const float* __restrict__ wq, const float* __restrict__ wk, const float* __restrict__ wv,
    const float* __restrict__ bq, const float* __restrict__ bk, const float* __restrict__ bv,
    _Float16* __restrict__ qo, _Float16* __restrict__ ko, _Float16* __restrict__ vo) {
  __shared__ __align__(16) _Float16 As[128 * 32];
  __shared__ __align__(16) _Float16 Bs[128 * 32];
  const int tid = threadIdx.x;
  const int wave = tid >> 6, lane = tid & 63;
  const int m15 = lane & 15, quad = lane >> 4;
  const int m0 = blockIdx.x * 128;
  const int gn0 = blockIdx.y * 128;
  const int sel = gn0 >> 10;       // 0:q 1:k 2:v (128 | 1024, no straddle)
  const int n0 = gn0 & 1023;
  const float* Ag = (sel == 0) ? Qf : (sel == 1) ? Kf : Vf;
  const float* Wg = (sel == 0) ? wq : (sel == 1) ? wk : wv;
  const float* bias = (sel == 0) ? bq : (sel == 1) ? bk : bv;
  _Float16* outp = (sel == 0) ? qo : (sel == 1) ? ko : vo;
  const float scale = (sel == 0) ? 0.125f : 1.0f;

  const int wm = (wave & 1) * 64, wn = (wave >> 1) * 64;
  const int sr = tid >> 1, sc16 = (tid & 1) * 16;  // staging coords: row, col

  f32x4 acc[4][4];
#pragma unroll
  for (int i = 0; i < 4; i++)
#pragma unroll
    for (int j = 0; j < 4; j++) {
      f32x4 z = {0.f, 0.f, 0.f, 0.f};
      acc[i][j] = z;
    }

  for (int k0 = 0; k0 < DMODEL; k0 += 32) {
    stage16_cvt(Ag + (size_t)(m0 + sr) * DMODEL + k0 + sc16, &As[sr * 32 + sc16]);
    stage16_cvt(Wg + (size_t)(n0 + sr) * DMODEL + k0 + sc16, &Bs[sr * 32 + sc16]);
    __syncthreads();
    half8 af[4], bf[4];
#pragma unroll
    for (int i = 0; i < 4; i++)
      af[i] = *(const half8*)&As[(wm + i * 16 + m15) * 32 + quad * 8];
#pragma unroll
    for (int j = 0; j < 4; j++)
      bf[j] = *(const half8*)&Bs[(wn + j * 16 + m15) * 32 + quad * 8];
#pragma unroll
    for (int i = 0; i < 4; i++)
#pragma unroll
      for (int j = 0; j < 4; j++)
        acc[i][j] = __builtin_amdgcn_mfma_f32_16x16x32_f16(af[i], bf[j], acc[i][j], 0, 0, 0);
    __syncthreads();
  }
  // epilogue: C/D layout col=lane&15, row=quad*4+r
#pragma unroll
  for (int i = 0; i < 4; i++) {
#pragma unroll
    for (int j = 0; j < 4; j++) {
      int gn = n0 + wn + j * 16 + m15;
      float bb = bias[gn];
#pragma unroll
      for (int r = 0; r < 4; r++) {
        int gm = m0 + wm + i * 16 + quad * 4 + r;
        outp[(size_t)gm * DMODEL + gn] = (_Float16)((acc[i][j][r] + bb) * scale);
      }
    }
  }
}

// ---------------- flash attention ----------------
// grid: (S/64, H, B), 256 threads (4 waves). Wave handles 16 q-rows; KV tile = 64.
__global__ __launch_bounds__(256) void attn_kernel(const _Float16* __restrict__ qh,
                                                   const _Float16* __restrict__ kh,
                                                   const _Float16* __restrict__ vh,
                                                   _Float16* __restrict__ ctx) {
  __shared__ __align__(16) _Float16 Vt[64 * 72];      // V^T tile, padded stride 72
  __shared__ __align__(16) _Float16 Pl[4][16 * 72];   // per-wave P, padded stride 72
  const int tid = threadIdx.x;
  const int wave = tid >> 6, lane = tid & 63;
  const int m15 = lane & 15, quad = lane >> 4;
  const int q0 = blockIdx.x * 64;
  const int h = blockIdx.y, b = blockIdx.z;
  const size_t base = (size_t)b * S_LEN * DMODEL + (size_t)h * DHEAD;

  // Q fragments (q already scaled by 1/sqrt(dk)): A-layout m=lane&15, k=quad*8+j
  const int qrow = q0 + wave * 16 + m15;
  half8 qf0 = *(const half8*)(qh + base + (size_t)qrow * DMODEL + quad * 8);
  half8 qf1 = *(const half8*)(qh + base + (size_t)qrow * DMODEL + 32 + quad * 8);

  f32x4 O[4];
#pragma unroll
  for (int i = 0; i < 4; i++) { f32x4 z = {0.f, 0.f, 0.f, 0.f}; O[i] = z; }
  float mrow[4] = {-1e30f, -1e30f, -1e30f, -1e30f};
  float lrow[4] = {0.f, 0.f, 0.f, 0.f};

  const int vs = tid >> 2, vc = (tid & 3) * 16;  // V staging coords

  for (int kv0 = 0; kv0 < S_LEN; kv0 += 64) {
    __syncthreads();  // protect Vt from previous iteration's readers
    // stage V tile transposed: Vt[dk][s']
    {
      const _Float16* vp = vh + base + (size_t)(kv0 + vs) * DMODEL + vc;
      half8 x0 = *(const half8*)vp;
      half8 x1 = *(const half8*)(vp + 8);
#pragma unroll
      for (int j = 0; j < 8; j++) {
        Vt[(vc + j) * 72 + vs] = x0[j];
        Vt[(vc + 8 + j) * 72 + vs] = x1[j];
      }
    }
    __syncthreads();

    // QK^T: 4 s'-tiles of 16, K frags straight from global (B-layout n=lane&15, k=quad*8+j)
    f32x4 sc[4];
#pragma unroll
    for (int t = 0; t < 4; t++) {
      const _Float16* kp = kh + base + (size_t)(kv0 + t * 16 + m15) * DMODEL + quad * 8;
      half8 kf0 = *(const half8*)kp;
      half8 kf1 = *(const half8*)(kp + 32);
      f32x4 z = {0.f, 0.f, 0.f, 0.f};
      sc[t] = __builtin_amdgcn_mfma_f32_16x16x32_f16(qf0, kf0, z, 0, 0, 0);
      sc[t] = __builtin_amdgcn_mfma_f32_16x16x32_f16(qf1, kf1, sc[t], 0, 0, 0);
    }

    // online softmax; rows live as quad*4+r, cols spread over 16 lanes
    float mx[4];
#pragma unroll
    for (int r = 0; r < 4; r++)
      mx[r] = fmaxf(fmaxf(sc[0][r], sc[1][r]), fmaxf(sc[2][r], sc[3][r]));
#pragma unroll
    for (int msk = 1; msk < 16; msk <<= 1)
#pragma unroll
      for (int r = 0; r < 4; r++) mx[r] = fmaxf(mx[r], __shfl_xor(mx[r], msk));

    float al[4];
#pragma unroll
    for (int r = 0; r < 4; r++) {
      float mn = fmaxf(mrow[r], mx[r]);
      al[r] = exp2f((mrow[r] - mn) * LOG2E);
      mrow[r] = mn;
    }
    float rs[4] = {0.f, 0.f, 0.f, 0.f};
#pragma unroll
    for (int t = 0; t < 4; t++)
#pragma unroll
      for (int r = 0; r < 4; r++) {
        float p = exp2f((sc[t][r] - mrow[r]) * LOG2E);
        sc[t][r] = p;
        rs[r] += p;
      }
#pragma unroll
    for (int msk = 1; msk < 16; msk <<= 1)
#pragma unroll
      for (int r = 0; r < 4; r++) rs[r] += __shfl_xor(rs[r], msk);
#pragma unroll
    for (int r = 0; r < 4; r++) lrow[r] = lrow[r] * al[r] + rs[r];
#pragma unroll
    for (int i = 0; i < 4; i++)
#pragma unroll
      for (int r = 0; r < 4; r++) O[i][r] *= al[r];

    // P: C-layout -> LDS -> A-layout (same-wave DS ops are in-order; per-wave buffer)
#pragma unroll
    for (int t = 0; t < 4; t++)
#pragma unroll
      for (int r = 0; r < 4; r++)
        Pl[wave][(quad * 4 + r) * 72 + t * 16 + m15] = (_Float16)sc[t][r];

    half8 pf0 = *(const half8*)&Pl[wave][m15 * 72 + quad * 8];
    half8 pf1 = *(const half8*)&Pl[wave][m15 * 72 + 32 + quad * 8];

    // PV: B operand from transposed V tile
#pragma unroll
    for (int t = 0; t < 4; t++) {
      half8 vf0 = *(const half8*)&Vt[(t * 16 + m15) * 72 + quad * 8];
      half8 vf1 = *(const half8*)&Vt[(t * 16 + m15) * 72 + 32 + quad * 8];
      O[t] = __builtin_amdgcn_mfma_f32_16x16x32_f16(pf0, vf0, O[t], 0, 0, 0);
      O[t] = __builtin_amdgcn_mfma_f32_16x16x32_f16(pf1, vf1, O[t], 0, 0, 0);
    }
  }

  // epilogue: ctx[b, row, h*64 + dk]
#pragma unroll
  for (int t = 0; t < 4; t++)
#pragma unroll
    for (int r = 0; r < 4; r++) {
      int row = q0 + wave * 16 + quad * 4 + r;
      ctx[base + (size_t)row * DMODEL + t * 16 + m15] = (_Float16)(O[t][r] / lrow[r]);
    }
}

// ---------------- output projection: fp32 out = ctx @ wo^T + bo ----------------
__global__ __launch_bounds__(256) void out_gemm(const _Float16* __restrict__ ch,
                                                const float* __restrict__ wo,
                                                const float* __restrict__ bo,
                                                float* __restrict__ out) {
  __shared__ __align__(16) _Float16 As[128 * 32];
  __shared__ __align__(16) _Float16 Bs[128 * 32];
  const int tid = threadIdx.x;
  const int wave = tid >> 6, lane = tid & 63;
  const int m15 = lane & 15, quad = lane >> 4;
  const int m0 = blockIdx.x * 128, n0 = blockIdx.y * 128;
  const int wm = (wave & 1) * 64, wn = (wave >> 1) * 64;
  const int sr = tid >> 1, sc16 = (tid & 1) * 16;

  f32x4 acc[4][4];
#pragma unroll
  for (int i = 0; i < 4; i++)
#pragma unroll
    for (int j = 0; j < 4; j++) {
      f32x4 z = {0.f, 0.f, 0.f, 0.f};
      acc[i][j] = z;
    }

  for (int k0 = 0; k0 < DMODEL; k0 += 32) {
    // A tile: ctx already fp16, plain vector loads + LDS store
    {
      const _Float16* ap = ch + (size_t)(m0 + sr) * DMODEL + k0 + sc16;
      half8 x0 = *(const half8*)ap;
      half8 x1 = *(const half8*)(ap + 8);
      *(half8*)&As[sr * 32 + sc16] = x0;
      *(half8*)&As[sr * 32 + sc16 + 8] = x1;
    }
    // B tile: wo fp32 -> fp16 inline
    stage16_cvt(wo + (size_t)(n0 + sr) * DMODEL + k0 + sc16, &Bs[sr * 32 + sc16]);
    __syncthreads();
    half8 af[4], bf[4];
#pragma unroll
    for (int i = 0; i < 4; i++)
      af[i] = *(const half8*)&As[(wm + i * 16 + m15) * 32 + quad * 8];
#pragma unroll
    for (int j = 0; j < 4; j++)
      bf[j] = *(const half8*)&Bs[(wn + j * 16 + m15) * 32 + quad * 8];
#pragma unroll
    for (int i = 0; i < 4; i++)
#pragma unroll
      for (int j = 0; j < 4; j++)
        acc[i][j] = __builtin_amdgcn_mfma_f32_16x16x32_f16(af[i], bf[j], acc[i][j], 0, 0, 0);
    __syncthreads();
  }
#pragma unroll
  for (int i = 0; i < 4; i++) {
#pragma unroll
    for (int j = 0; j < 4; j++) {
      int gn = n0 + wn + j * 16 + m15;
      float bb = bo[gn];
#pragma unroll
      for (int r = 0; r < 4; r++) {
        int gm = m0 + wm + i * 16 + quad * 4 + r;
        out[(size_t)gm * DMODEL + gn] = acc[i][j][r] + bb;
      }
    }
  }
}

extern "C" void kernel_launch(void* const* d_in, const int* in_sizes, int n_in,
                              void* d_out, int out_size, void* d_ws, size_t ws_size,
                              hipStream_t stream) {
  (void)in_sizes; (void)n_in; (void)out_size; (void)ws_size;
  const float* Q  = (const float*)d_in[0];
  const float* K  = (const float*)d_in[1];
  const float* V  = (const float*)d_in[2];
  const float* wq = (const float*)d_in[3];
  const float* bq = (const float*)d_in[4];
  const float* wk = (const float*)d_in[5];
  const float* bk = (const float*)d_in[6];
  const float* wv = (const float*)d_in[7];
  const float* bv = (const float*)d_in[8];
  const float* wo = (const float*)d_in[9];
  const float* bo = (const float*)d_in[10];
  float* out = (float*)d_out;

  // Scratch plan (keeps d_ws need at 16 MB):
  //   q,k (fp16, 8 MB each) live inside d_out (16 MB fp32) — dead before out_gemm writes it.
  //   v,ctx (fp16, 8 MB each) live in d_ws.
  _Float16* qh = (_Float16*)d_out;
  _Float16* kh = qh + (size_t)4194304;
  _Float16* vh = (_Float16*)d_ws;
  _Float16* ch = vh + (size_t)4194304;

  qkv_gemm<<<dim3(32, 24), 256, 0, stream>>>(Q, K, V, wq, wk, wv, bq, bk, bv, qh, kh, vh);
  attn_kernel<<<dim3(32, 16, 2), 256, 0, stream>>>(qh, kh, vh, ch);
  out_gemm<<<dim3(32, 8), 256, 0, stream>>>(ch, wo, bo, out);
}